// Round 2
// baseline (220.804 us; speedup 1.0000x reference)
//
#include <hip/hip_runtime.h>

#define BATCH 16
#define NCLS 80
#define FH 128
#define FW 128
#define HW (FH*FW)
#define MAXO 100
#define NOBJ (BATCH*MAXO)

#define SPLIT 4              // blocks per (b,c) channel
#define PXB (HW/SPLIT)       // 4096 pixels per block
#define F4B (PXB/4)          // 1024 float4 per block
#define ITERS (F4B/256)      // 4 float4 per thread

__device__ __forceinline__ float smooth_l1(float x) {
    const float F = 1.0f/9.0f;
    return (x >= F) ? (x - 0.5f*F) : (0.5f*x*x/F);
}

// Per-object target prep: mirrors _per_image_targets scalar math.
// Also zeroes the global accumulators (runs before focal_kernel on the stream).
__global__ void prep_kernel(const float* __restrict__ annot,
                            float4* __restrict__ objp,   // cxi, cyi, r, -1/(2*sigma^2)
                            float4* __restrict__ objt,   // off_x, off_y, wh_w, wh_h
                            int*    __restrict__ objc,   // class id, -1 if invalid
                            int*    __restrict__ objreg, // flattened HW index
                            float*  __restrict__ objm,   // valid mask (0/1)
                            float*  __restrict__ accum)  // [pos_loss, neg_loss, pos_num, pad]
{
    int o = blockIdx.x*blockDim.x + threadIdx.x;
    if (o < 4) accum[o] = 0.0f;
    if (o >= NOBJ) return;
    const float* a = annot + (size_t)o*5;
    float clsf = a[4];
    bool valid = (clsf >= 0.0f);
    float vf = valid ? 1.0f : 0.0f;
    float x1 = fminf(fmaxf(a[0]*0.25f, 0.0f), (float)(FW-1));
    float y1 = fminf(fmaxf(a[1]*0.25f, 0.0f), (float)(FH-1));
    float x2 = fminf(fmaxf(a[2]*0.25f, 0.0f), (float)(FW-1));
    float y2 = fminf(fmaxf(a[3]*0.25f, 0.0f), (float)(FH-1));
    float bw = x2 - x1, bh = y2 - y1;
    float cx = (x1 + x2)*0.5f, cy = (y1 + y2)*0.5f;
    float cxi = truncf(cx), cyi = truncf(cy);
    float offx = (cx - cxi)*vf, offy = (cy - cyi)*vf;
    float whw = bw*vf, whh = bh*vf;
    float ridx = (cyi*(float)FW + cxi)*vf;
    float h = ceilf(bh), w = ceilf(bw);
    const float MO = 0.7f;
    float b1 = h + w;
    float c1 = w*h*(1.0f - MO)/(1.0f + MO);
    float r1 = (b1 + sqrtf(b1*b1 - 4.0f*c1))*0.5f;
    float b2 = 2.0f*(h + w);
    float c2 = (1.0f - MO)*w*h;
    float r2 = (b2 + sqrtf(b2*b2 - 16.0f*c2))*0.5f;
    float a3 = 4.0f*MO;
    float b3 = -2.0f*MO*(h + w);
    float c3 = (MO - 1.0f)*w*h;
    float r3 = (b3 + sqrtf(b3*b3 - 4.0f*a3*c3))/(2.0f*a3);
    float r = fminf(fminf(r1, r2), r3);
    r = fmaxf(0.0f, truncf(r));
    float sigma = (2.0f*r + 1.0f)/6.0f;
    float coef = -1.0f/(2.0f*sigma*sigma);
    objp[o] = make_float4(cxi, cyi, r, coef);
    objt[o] = make_float4(offx, offy, whw, whh);
    objc[o] = valid ? (int)clsf : -1;
    objreg[o] = (int)ridx;
    objm[o] = vf;
}

// SPLIT blocks per (b, c) channel; hm_t computed on the fly from the
// compacted per-class object list (avg ~1.25 objects/channel).
__launch_bounds__(256)
__global__ void focal_kernel(const float4* __restrict__ heat,
                             const float4* __restrict__ objp,
                             const int*    __restrict__ objc,
                             float*        __restrict__ accum)
{
    int blk = blockIdx.x;
    int chan = blk / SPLIT;           // (b*NCLS + c)
    int part = blk - chan*SPLIT;
    int b = chan / NCLS;
    int c = chan - b*NCLS;
    __shared__ float sx[MAXO], sy[MAXO], sr[MAXO], sk[MAXO];
    __shared__ int scnt;
    __shared__ float wred[3][4];
    if (threadIdx.x == 0) scnt = 0;
    __syncthreads();
    if (threadIdx.x < MAXO) {
        int o = b*MAXO + threadIdx.x;
        if (objc[o] == c) {
            int s = atomicAdd(&scnt, 1);
            float4 p = objp[o];
            sx[s] = p.x; sy[s] = p.y; sr[s] = p.z; sk[s] = p.w;
        }
    }
    __syncthreads();
    int cnt = scnt;
    const float4* hp = heat + (size_t)chan*(HW/4) + (size_t)part*F4B;
    int pixbase = part*PXB;
    float ploss = 0.0f, nloss = 0.0f, pnum = 0.0f;
    #pragma unroll
    for (int it = 0; it < ITERS; ++it) {
        int q = it*256 + threadIdx.x;
        float4 h4 = hp[q];
        int pix = pixbase + q*4;
        float fy = (float)(pix >> 7);
        float fx0 = (float)(pix & (FW-1));
        float hv[4] = {h4.x, h4.y, h4.z, h4.w};
        #pragma unroll
        for (int k = 0; k < 4; ++k) {
            float fx = fx0 + (float)k;
            float gmax = 0.0f;
            for (int j = 0; j < cnt; ++j) {
                float dx = fx - sx[j], dy = fy - sy[j];
                float r = sr[j];
                if (fabsf(dx) <= r && fabsf(dy) <= r) {
                    gmax = fmaxf(gmax, __expf(sk[j]*(dx*dx + dy*dy)));
                }
            }
            float p = fminf(fmaxf(hv[k], 1.0e-4f), 1.0f - 1.0e-4f);
            if (gmax == 1.0f) {
                float om = 1.0f - p;
                ploss += -__logf(p)*om*om;
                pnum += 1.0f;
            } else {
                float og = 1.0f - gmax;
                float w2 = og*og;
                nloss += -__logf(1.0f - p)*p*p*(w2*w2);
            }
        }
    }
    #pragma unroll
    for (int off = 32; off > 0; off >>= 1) {
        ploss += __shfl_down(ploss, off);
        nloss += __shfl_down(nloss, off);
        pnum  += __shfl_down(pnum,  off);
    }
    int lane = threadIdx.x & 63, wid = threadIdx.x >> 6;
    if (lane == 0) { wred[0][wid] = ploss; wred[1][wid] = nloss; wred[2][wid] = pnum; }
    __syncthreads();
    if (threadIdx.x == 0) {
        float P = 0.0f, N = 0.0f, Q = 0.0f;
        #pragma unroll
        for (int i = 0; i < 4; ++i) { P += wred[0][i]; N += wred[1][i]; Q += wred[2][i]; }
        atomicAdd(&accum[0], P);
        atomicAdd(&accum[1], N);
        atomicAdd(&accum[2], Q);
    }
}

// Smooth-L1 gathers for offset/wh + final combine. One block.
__launch_bounds__(256)
__global__ void reg_kernel(const float* __restrict__ offp,
                           const float* __restrict__ whp,
                           const float4* __restrict__ objt,
                           const int*    __restrict__ objreg,
                           const float*  __restrict__ objm,
                           const float*  __restrict__ accum,
                           float*        __restrict__ out)
{
    float loff = 0.0f, lwh = 0.0f, n = 0.0f;
    for (int o = threadIdx.x; o < NOBJ; o += blockDim.x) {
        int b = o / MAXO;
        float m = objm[o];
        int idx = objreg[o];
        float4 t = objt[o];
        const float* ob = offp + (size_t)b*2*HW;
        const float* wb = whp  + (size_t)b*2*HW;
        float p0 = ob[idx], p1 = ob[HW + idx];
        float q0 = wb[idx], q1 = wb[HW + idx];
        loff += smooth_l1(fabsf(p0*m - t.x*m)) + smooth_l1(fabsf(p1*m - t.y*m));
        lwh  += smooth_l1(fabsf(q0*m - t.z*m)) + smooth_l1(fabsf(q1*m - t.w*m));
        n += m;
    }
    __shared__ float wred[3][4];
    #pragma unroll
    for (int off = 32; off > 0; off >>= 1) {
        loff += __shfl_down(loff, off);
        lwh  += __shfl_down(lwh,  off);
        n    += __shfl_down(n,    off);
    }
    int lane = threadIdx.x & 63, wid = threadIdx.x >> 6;
    if (lane == 0) { wred[0][wid] = loff; wred[1][wid] = lwh; wred[2][wid] = n; }
    __syncthreads();
    if (threadIdx.x == 0) {
        float LO = 0.0f, LW = 0.0f, NN = 0.0f;
        #pragma unroll
        for (int i = 0; i < 4; ++i) { LO += wred[0][i]; LW += wred[1][i]; NN += wred[2][i]; }
        float pn = accum[2];
        float hm = (pn > 0.0f) ? (accum[0] + accum[1])/fmaxf(pn, 1.0f) : 0.0f;
        float ol = (NN > 0.0f) ? LO/fmaxf(NN, 1.0f) : 0.0f;
        float wl = (NN > 0.0f) ? LW/fmaxf(NN, 1.0f) : 0.0f;
        out[0] = 1.0f*hm;   // HM_W
        out[1] = 1.0f*ol;   // OFF_W
        out[2] = 0.1f*wl;   // WH_W
    }
}

extern "C" void kernel_launch(void* const* d_in, const int* in_sizes, int n_in,
                              void* d_out, int out_size, void* d_ws, size_t ws_size,
                              hipStream_t stream) {
    const float* heat  = (const float*)d_in[0];  // (16,80,128,128)
    const float* offp  = (const float*)d_in[1];  // (16,2,128,128)
    const float* whp   = (const float*)d_in[2];  // (16,2,128,128)
    const float* annot = (const float*)d_in[3];  // (16,100,5)
    float* out = (float*)d_out;                  // (3,)

    char* ws = (char*)d_ws;
    float4* objp = (float4*)ws;  ws += sizeof(float4)*NOBJ;
    float4* objt = (float4*)ws;  ws += sizeof(float4)*NOBJ;
    float*  accum = (float*)ws;  ws += sizeof(float)*4;
    float*  objm = (float*)ws;   ws += sizeof(float)*NOBJ;
    int*    objc = (int*)ws;     ws += sizeof(int)*NOBJ;
    int*    objreg = (int*)ws;   ws += sizeof(int)*NOBJ;

    prep_kernel<<<(NOBJ + 255)/256, 256, 0, stream>>>(annot, objp, objt, objc, objreg, objm, accum);
    focal_kernel<<<BATCH*NCLS*SPLIT, 256, 0, stream>>>((const float4*)heat, objp, objc, accum);
    reg_kernel<<<1, 256, 0, stream>>>(offp, whp, objt, objreg, objm, accum, out);
}

// Round 3
// 52.926 us; speedup vs baseline: 4.1719x; 4.1719x over previous
//
#include <hip/hip_runtime.h>

#define BATCH 16
#define NCLS 80
#define FH 128
#define FW 128
#define HW (FH*FW)
#define MAXO 100
#define NOBJ (BATCH*MAXO)

#define SPLIT 4              // blocks per (b,c) channel
#define NPART (BATCH*NCLS*SPLIT)
#define PXB (HW/SPLIT)       // 4096 pixels per block
#define F4B (PXB/4)          // 1024 float4 per block
#define ITERS (F4B/256)      // 4 float4 per thread

__device__ __forceinline__ float smooth_l1(float x) {
    const float F = 1.0f/9.0f;
    return (x >= F) ? (x - 0.5f*F) : (0.5f*x*x/F);
}

// Per-object target prep: mirrors _per_image_targets scalar math.
__global__ void prep_kernel(const float* __restrict__ annot,
                            float4* __restrict__ objp,   // cxi, cyi, r, -1/(2*sigma^2)
                            float4* __restrict__ objt,   // off_x, off_y, wh_w, wh_h
                            int*    __restrict__ objc,   // class id, -1 if invalid
                            int*    __restrict__ objreg, // flattened HW index
                            float*  __restrict__ objm)   // valid mask (0/1)
{
    int o = blockIdx.x*blockDim.x + threadIdx.x;
    if (o >= NOBJ) return;
    const float* a = annot + (size_t)o*5;
    float clsf = a[4];
    bool valid = (clsf >= 0.0f);
    float vf = valid ? 1.0f : 0.0f;
    float x1 = fminf(fmaxf(a[0]*0.25f, 0.0f), (float)(FW-1));
    float y1 = fminf(fmaxf(a[1]*0.25f, 0.0f), (float)(FH-1));
    float x2 = fminf(fmaxf(a[2]*0.25f, 0.0f), (float)(FW-1));
    float y2 = fminf(fmaxf(a[3]*0.25f, 0.0f), (float)(FH-1));
    float bw = x2 - x1, bh = y2 - y1;
    float cx = (x1 + x2)*0.5f, cy = (y1 + y2)*0.5f;
    float cxi = truncf(cx), cyi = truncf(cy);
    float offx = (cx - cxi)*vf, offy = (cy - cyi)*vf;
    float whw = bw*vf, whh = bh*vf;
    float ridx = (cyi*(float)FW + cxi)*vf;
    float h = ceilf(bh), w = ceilf(bw);
    const float MO = 0.7f;
    float b1 = h + w;
    float c1 = w*h*(1.0f - MO)/(1.0f + MO);
    float r1 = (b1 + sqrtf(b1*b1 - 4.0f*c1))*0.5f;
    float b2 = 2.0f*(h + w);
    float c2 = (1.0f - MO)*w*h;
    float r2 = (b2 + sqrtf(b2*b2 - 16.0f*c2))*0.5f;
    float a3 = 4.0f*MO;
    float b3 = -2.0f*MO*(h + w);
    float c3 = (MO - 1.0f)*w*h;
    float r3 = (b3 + sqrtf(b3*b3 - 4.0f*a3*c3))/(2.0f*a3);
    float r = fminf(fminf(r1, r2), r3);
    r = fmaxf(0.0f, truncf(r));
    float sigma = (2.0f*r + 1.0f)/6.0f;
    float coef = -1.0f/(2.0f*sigma*sigma);
    objp[o] = make_float4(cxi, cyi, r, coef);
    objt[o] = make_float4(offx, offy, whw, whh);
    objc[o] = valid ? (int)clsf : -1;
    objreg[o] = (int)ridx;
    objm[o] = vf;
}

// SPLIT blocks per (b, c) channel; hm_t computed on the fly from the
// compacted per-class object list. NO global atomics: per-block partial
// (pos_loss, neg_loss, pos_num) written to part[blk].
__launch_bounds__(256)
__global__ void focal_kernel(const float4* __restrict__ heat,
                             const float4* __restrict__ objp,
                             const int*    __restrict__ objc,
                             float4*       __restrict__ part)
{
    int blk = blockIdx.x;
    int chan = blk / SPLIT;           // (b*NCLS + c)
    int partid = blk - chan*SPLIT;
    int b = chan / NCLS;
    int c = chan - b*NCLS;
    __shared__ float sx[MAXO], sy[MAXO], sr[MAXO], sk[MAXO];
    __shared__ int scnt;
    __shared__ float wred[3][4];
    if (threadIdx.x == 0) scnt = 0;
    __syncthreads();
    if (threadIdx.x < MAXO) {
        int o = b*MAXO + threadIdx.x;
        if (objc[o] == c) {
            int s = atomicAdd(&scnt, 1);
            float4 p = objp[o];
            sx[s] = p.x; sy[s] = p.y; sr[s] = p.z; sk[s] = p.w;
        }
    }
    __syncthreads();
    int cnt = scnt;
    const float4* hp = heat + (size_t)chan*(HW/4) + (size_t)partid*F4B;
    int pixbase = partid*PXB;
    float ploss = 0.0f, nloss = 0.0f, pnum = 0.0f;
    #pragma unroll
    for (int it = 0; it < ITERS; ++it) {
        int q = it*256 + threadIdx.x;
        float4 h4 = hp[q];
        int pix = pixbase + q*4;
        float fy = (float)(pix >> 7);
        float fx0 = (float)(pix & (FW-1));
        float hv[4] = {h4.x, h4.y, h4.z, h4.w};
        #pragma unroll
        for (int k = 0; k < 4; ++k) {
            float fx = fx0 + (float)k;
            float gmax = 0.0f;
            for (int j = 0; j < cnt; ++j) {
                float dx = fx - sx[j], dy = fy - sy[j];
                float r = sr[j];
                if (fabsf(dx) <= r && fabsf(dy) <= r) {
                    gmax = fmaxf(gmax, __expf(sk[j]*(dx*dx + dy*dy)));
                }
            }
            float p = fminf(fmaxf(hv[k], 1.0e-4f), 1.0f - 1.0e-4f);
            if (gmax == 1.0f) {
                float om = 1.0f - p;
                ploss += -__logf(p)*om*om;
                pnum += 1.0f;
            } else {
                float og = 1.0f - gmax;
                float w2 = og*og;
                nloss += -__logf(1.0f - p)*p*p*(w2*w2);
            }
        }
    }
    #pragma unroll
    for (int off = 32; off > 0; off >>= 1) {
        ploss += __shfl_down(ploss, off);
        nloss += __shfl_down(nloss, off);
        pnum  += __shfl_down(pnum,  off);
    }
    int lane = threadIdx.x & 63, wid = threadIdx.x >> 6;
    if (lane == 0) { wred[0][wid] = ploss; wred[1][wid] = nloss; wred[2][wid] = pnum; }
    __syncthreads();
    if (threadIdx.x == 0) {
        float P = 0.0f, N = 0.0f, Q = 0.0f;
        #pragma unroll
        for (int i = 0; i < 4; ++i) { P += wred[0][i]; N += wred[1][i]; Q += wred[2][i]; }
        part[blk] = make_float4(P, N, Q, 0.0f);
    }
}

// Reduce focal partials + smooth-L1 gathers + final combine. One block.
__launch_bounds__(256)
__global__ void reg_kernel(const float* __restrict__ offp,
                           const float* __restrict__ whp,
                           const float4* __restrict__ objt,
                           const int*    __restrict__ objreg,
                           const float*  __restrict__ objm,
                           const float4* __restrict__ part,
                           float*        __restrict__ out)
{
    // focal partial reduction
    float P = 0.0f, N = 0.0f, Q = 0.0f;
    for (int i = threadIdx.x; i < NPART; i += blockDim.x) {
        float4 v = part[i];
        P += v.x; N += v.y; Q += v.z;
    }
    // smooth-L1 gathers
    float loff = 0.0f, lwh = 0.0f, n = 0.0f;
    for (int o = threadIdx.x; o < NOBJ; o += blockDim.x) {
        int b = o / MAXO;
        float m = objm[o];
        int idx = objreg[o];
        float4 t = objt[o];
        const float* ob = offp + (size_t)b*2*HW;
        const float* wb = whp  + (size_t)b*2*HW;
        float p0 = ob[idx], p1 = ob[HW + idx];
        float q0 = wb[idx], q1 = wb[HW + idx];
        loff += smooth_l1(fabsf(p0*m - t.x*m)) + smooth_l1(fabsf(p1*m - t.y*m));
        lwh  += smooth_l1(fabsf(q0*m - t.z*m)) + smooth_l1(fabsf(q1*m - t.w*m));
        n += m;
    }
    __shared__ float wred[6][4];
    #pragma unroll
    for (int off = 32; off > 0; off >>= 1) {
        P    += __shfl_down(P,    off);
        N    += __shfl_down(N,    off);
        Q    += __shfl_down(Q,    off);
        loff += __shfl_down(loff, off);
        lwh  += __shfl_down(lwh,  off);
        n    += __shfl_down(n,    off);
    }
    int lane = threadIdx.x & 63, wid = threadIdx.x >> 6;
    if (lane == 0) {
        wred[0][wid] = P; wred[1][wid] = N; wred[2][wid] = Q;
        wred[3][wid] = loff; wred[4][wid] = lwh; wred[5][wid] = n;
    }
    __syncthreads();
    if (threadIdx.x == 0) {
        float s[6];
        #pragma unroll
        for (int r = 0; r < 6; ++r) {
            s[r] = wred[r][0] + wred[r][1] + wred[r][2] + wred[r][3];
        }
        float pn = s[2];
        float hm = (pn > 0.0f) ? (s[0] + s[1])/fmaxf(pn, 1.0f) : 0.0f;
        float ol = (s[5] > 0.0f) ? s[3]/fmaxf(s[5], 1.0f) : 0.0f;
        float wl = (s[5] > 0.0f) ? s[4]/fmaxf(s[5], 1.0f) : 0.0f;
        out[0] = 1.0f*hm;   // HM_W
        out[1] = 1.0f*ol;   // OFF_W
        out[2] = 0.1f*wl;   // WH_W
    }
}

extern "C" void kernel_launch(void* const* d_in, const int* in_sizes, int n_in,
                              void* d_out, int out_size, void* d_ws, size_t ws_size,
                              hipStream_t stream) {
    const float* heat  = (const float*)d_in[0];  // (16,80,128,128)
    const float* offp  = (const float*)d_in[1];  // (16,2,128,128)
    const float* whp   = (const float*)d_in[2];  // (16,2,128,128)
    const float* annot = (const float*)d_in[3];  // (16,100,5)
    float* out = (float*)d_out;                  // (3,)

    char* ws = (char*)d_ws;
    float4* objp = (float4*)ws;  ws += sizeof(float4)*NOBJ;
    float4* objt = (float4*)ws;  ws += sizeof(float4)*NOBJ;
    float4* part = (float4*)ws;  ws += sizeof(float4)*NPART;
    float*  objm = (float*)ws;   ws += sizeof(float)*NOBJ;
    int*    objc = (int*)ws;     ws += sizeof(int)*NOBJ;
    int*    objreg = (int*)ws;   ws += sizeof(int)*NOBJ;

    prep_kernel<<<(NOBJ + 255)/256, 256, 0, stream>>>(annot, objp, objt, objc, objreg, objm);
    focal_kernel<<<NPART, 256, 0, stream>>>((const float4*)heat, objp, objc, part);
    reg_kernel<<<1, 256, 0, stream>>>(offp, whp, objt, objreg, objm, part, out);
}

// Round 4
// 50.860 us; speedup vs baseline: 4.3414x; 1.0406x over previous
//
#include <hip/hip_runtime.h>

#define BATCH 16
#define NCLS 80
#define FH 128
#define FW 128
#define HW (FH*FW)
#define MAXO 100
#define NOBJ (BATCH*MAXO)

#define SPLIT 4              // blocks per (b,c) channel
#define NPART (BATCH*NCLS*SPLIT)
#define PXB (HW/SPLIT)       // 4096 pixels per block
#define F4B (PXB/4)          // 1024 float4 per block
#define ITERS (F4B/256)      // 4 float4 per thread

__device__ __forceinline__ float smooth_l1(float x) {
    const float F = 1.0f/9.0f;
    return (x >= F) ? (x - 0.5f*F) : (0.5f*x*x/F);
}

// Gaussian params for one annotation row. Returns false if invalid.
__device__ __forceinline__ bool obj_gauss(const float* a, float& cxi, float& cyi,
                                          float& r, float& coef, int& cls) {
    float clsf = a[4];
    if (!(clsf >= 0.0f)) { cls = -1; return false; }
    cls = (int)clsf;
    float x1 = fminf(fmaxf(a[0]*0.25f, 0.0f), (float)(FW-1));
    float y1 = fminf(fmaxf(a[1]*0.25f, 0.0f), (float)(FH-1));
    float x2 = fminf(fmaxf(a[2]*0.25f, 0.0f), (float)(FW-1));
    float y2 = fminf(fmaxf(a[3]*0.25f, 0.0f), (float)(FH-1));
    float bw = x2 - x1, bh = y2 - y1;
    cxi = truncf((x1 + x2)*0.5f);
    cyi = truncf((y1 + y2)*0.5f);
    float h = ceilf(bh), w = ceilf(bw);
    const float MO = 0.7f;
    float b1 = h + w;
    float c1 = w*h*(1.0f - MO)/(1.0f + MO);
    float r1 = (b1 + sqrtf(b1*b1 - 4.0f*c1))*0.5f;
    float b2 = 2.0f*(h + w);
    float c2 = (1.0f - MO)*w*h;
    float r2 = (b2 + sqrtf(b2*b2 - 16.0f*c2))*0.5f;
    float a3 = 4.0f*MO;
    float b3 = -2.0f*MO*(h + w);
    float c3 = (MO - 1.0f)*w*h;
    float r3 = (b3 + sqrtf(b3*b3 - 4.0f*a3*c3))/(2.0f*a3);
    r = fmaxf(0.0f, truncf(fminf(fminf(r1, r2), r3)));
    float sigma = (2.0f*r + 1.0f)/6.0f;
    coef = -1.0f/(2.0f*sigma*sigma);
    return true;
}

// SPLIT blocks per (b,c) channel. Builds its own per-class object list from
// annotations (no prep kernel), computes hm_t on the fly, writes one
// (pos_loss, neg_loss, pos_num) partial per block. No global atomics.
__launch_bounds__(256)
__global__ void focal_kernel(const float4* __restrict__ heat,
                             const float*  __restrict__ annot,
                             float4*       __restrict__ part)
{
    int blk = blockIdx.x;
    int chan = blk / SPLIT;           // (b*NCLS + c)
    int partid = blk - chan*SPLIT;
    int b = chan / NCLS;
    int c = chan - b*NCLS;
    __shared__ float sx[MAXO], sy[MAXO], sr[MAXO], sk[MAXO];
    __shared__ int scnt;
    __shared__ float wred[3][4];
    if (threadIdx.x == 0) scnt = 0;
    __syncthreads();
    if (threadIdx.x < MAXO) {
        const float* a = annot + ((size_t)b*MAXO + threadIdx.x)*5;
        float cxi, cyi, r, coef; int cls;
        if (obj_gauss(a, cxi, cyi, r, coef, cls) && cls == c) {
            int s = atomicAdd(&scnt, 1);
            sx[s] = cxi; sy[s] = cyi; sr[s] = r; sk[s] = coef;
        }
    }
    __syncthreads();
    int cnt = scnt;
    const float4* hp = heat + (size_t)chan*(HW/4) + (size_t)partid*F4B;
    int pixbase = partid*PXB;

    // Load-first: keep all ITERS float4 loads in flight before computing.
    float4 h[ITERS];
    #pragma unroll
    for (int it = 0; it < ITERS; ++it) {
        h[it] = hp[it*256 + threadIdx.x];
    }

    float ploss = 0.0f, nloss = 0.0f, pnum = 0.0f;
    #pragma unroll
    for (int it = 0; it < ITERS; ++it) {
        int pix = pixbase + (it*256 + threadIdx.x)*4;
        float fy = (float)(pix >> 7);
        float fx0 = (float)(pix & (FW-1));
        float hv[4] = {h[it].x, h[it].y, h[it].z, h[it].w};
        #pragma unroll
        for (int k = 0; k < 4; ++k) {
            float fx = fx0 + (float)k;
            float gmax = 0.0f;
            for (int j = 0; j < cnt; ++j) {
                float dx = fx - sx[j], dy = fy - sy[j];
                float r = sr[j];
                if (fabsf(dx) <= r && fabsf(dy) <= r) {
                    gmax = fmaxf(gmax, __expf(sk[j]*(dx*dx + dy*dy)));
                }
            }
            float p = fminf(fmaxf(hv[k], 1.0e-4f), 1.0f - 1.0e-4f);
            if (gmax == 1.0f) {
                float om = 1.0f - p;
                ploss += -__logf(p)*om*om;
                pnum += 1.0f;
            } else {
                float og = 1.0f - gmax;
                float w2 = og*og;
                nloss += -__logf(1.0f - p)*p*p*(w2*w2);
            }
        }
    }
    #pragma unroll
    for (int off = 32; off > 0; off >>= 1) {
        ploss += __shfl_down(ploss, off);
        nloss += __shfl_down(nloss, off);
        pnum  += __shfl_down(pnum,  off);
    }
    int lane = threadIdx.x & 63, wid = threadIdx.x >> 6;
    if (lane == 0) { wred[0][wid] = ploss; wred[1][wid] = nloss; wred[2][wid] = pnum; }
    __syncthreads();
    if (threadIdx.x == 0) {
        float P = 0.0f, N = 0.0f, Q = 0.0f;
        #pragma unroll
        for (int i = 0; i < 4; ++i) { P += wred[0][i]; N += wred[1][i]; Q += wred[2][i]; }
        part[blk] = make_float4(P, N, Q, 0.0f);
    }
}

// Reduce focal partials + per-object target math + smooth-L1 gathers. One block.
__launch_bounds__(256)
__global__ void reg_kernel(const float* __restrict__ offp,
                           const float* __restrict__ whp,
                           const float* __restrict__ annot,
                           const float4* __restrict__ part,
                           float*        __restrict__ out)
{
    // focal partial reduction
    float P = 0.0f, N = 0.0f, Q = 0.0f;
    for (int i = threadIdx.x; i < NPART; i += blockDim.x) {
        float4 v = part[i];
        P += v.x; N += v.y; Q += v.z;
    }
    // per-object targets + smooth-L1 gathers
    float loff = 0.0f, lwh = 0.0f, n = 0.0f;
    for (int o = threadIdx.x; o < NOBJ; o += blockDim.x) {
        int b = o / MAXO;
        const float* a = annot + (size_t)o*5;
        float clsf = a[4];
        float m = (clsf >= 0.0f) ? 1.0f : 0.0f;
        float x1 = fminf(fmaxf(a[0]*0.25f, 0.0f), (float)(FW-1));
        float y1 = fminf(fmaxf(a[1]*0.25f, 0.0f), (float)(FH-1));
        float x2 = fminf(fmaxf(a[2]*0.25f, 0.0f), (float)(FW-1));
        float y2 = fminf(fmaxf(a[3]*0.25f, 0.0f), (float)(FH-1));
        float cx = (x1 + x2)*0.5f, cy = (y1 + y2)*0.5f;
        float cxi = truncf(cx), cyi = truncf(cy);
        float tx = (cx - cxi)*m, ty = (cy - cyi)*m;
        float tw = (x2 - x1)*m, th = (y2 - y1)*m;
        int idx = (int)((cyi*(float)FW + cxi)*m);
        const float* ob = offp + (size_t)b*2*HW;
        const float* wb = whp  + (size_t)b*2*HW;
        float p0 = ob[idx], p1 = ob[HW + idx];
        float q0 = wb[idx], q1 = wb[HW + idx];
        loff += smooth_l1(fabsf(p0*m - tx*m)) + smooth_l1(fabsf(p1*m - ty*m));
        lwh  += smooth_l1(fabsf(q0*m - tw*m)) + smooth_l1(fabsf(q1*m - th*m));
        n += m;
    }
    __shared__ float wred[6][4];
    #pragma unroll
    for (int off = 32; off > 0; off >>= 1) {
        P    += __shfl_down(P,    off);
        N    += __shfl_down(N,    off);
        Q    += __shfl_down(Q,    off);
        loff += __shfl_down(loff, off);
        lwh  += __shfl_down(lwh,  off);
        n    += __shfl_down(n,    off);
    }
    int lane = threadIdx.x & 63, wid = threadIdx.x >> 6;
    if (lane == 0) {
        wred[0][wid] = P; wred[1][wid] = N; wred[2][wid] = Q;
        wred[3][wid] = loff; wred[4][wid] = lwh; wred[5][wid] = n;
    }
    __syncthreads();
    if (threadIdx.x == 0) {
        float s[6];
        #pragma unroll
        for (int r = 0; r < 6; ++r) {
            s[r] = wred[r][0] + wred[r][1] + wred[r][2] + wred[r][3];
        }
        float pn = s[2];
        float hm = (pn > 0.0f) ? (s[0] + s[1])/fmaxf(pn, 1.0f) : 0.0f;
        float ol = (s[5] > 0.0f) ? s[3]/fmaxf(s[5], 1.0f) : 0.0f;
        float wl = (s[5] > 0.0f) ? s[4]/fmaxf(s[5], 1.0f) : 0.0f;
        out[0] = 1.0f*hm;   // HM_W
        out[1] = 1.0f*ol;   // OFF_W
        out[2] = 0.1f*wl;   // WH_W
    }
}

extern "C" void kernel_launch(void* const* d_in, const int* in_sizes, int n_in,
                              void* d_out, int out_size, void* d_ws, size_t ws_size,
                              hipStream_t stream) {
    const float* heat  = (const float*)d_in[0];  // (16,80,128,128)
    const float* offp  = (const float*)d_in[1];  // (16,2,128,128)
    const float* whp   = (const float*)d_in[2];  // (16,2,128,128)
    const float* annot = (const float*)d_in[3];  // (16,100,5)
    float* out = (float*)d_out;                  // (3,)

    float4* part = (float4*)d_ws;                // NPART partials

    focal_kernel<<<NPART, 256, 0, stream>>>((const float4*)heat, annot, part);
    reg_kernel<<<1, 256, 0, stream>>>(offp, whp, annot, part, out);
}